// Round 3
// baseline (10494.702 us; speedup 1.0000x reference)
//
#include <hip/hip_runtime.h>
#include <cstdint>
#include <cstddef>

#define BB 128    // batch
#define TT 80     // seq
#define EE 100    // emb dim
#define EP 128    // padded emb dim
#define UU 2048   // units
#define G3 6144   // 3*UU
#define PLANE (BB * UU)   // 262144 elements, one gate pre-activation plane

typedef __bf16 bf16x8 __attribute__((ext_vector_type(8)));
typedef float f32x4 __attribute__((ext_vector_type(4)));
typedef int   i32x4 __attribute__((ext_vector_type(4)));

static __device__ __forceinline__ unsigned short f2bf(float x) {
  union { float f; unsigned int u; } a; a.f = x;
  unsigned int r = a.u + 0x7fffu + ((a.u >> 16) & 1u);  // RNE
  return (unsigned short)(r >> 16);
}

static __device__ __forceinline__ float sigf(float x) {
  return 1.f / (1.f + __expf(-x));
}
static __device__ __forceinline__ float tanhfast(float x) {
  return 1.f - 2.f / (__expf(2.f * x) + 1.f);
}

// accumulate 8 bf16 plane values (one int4 load) into float[8]
static __device__ __forceinline__ void acc8(float* s, const unsigned short* p) {
  int4 v = *reinterpret_cast<const int4*>(p);
  unsigned int w0 = (unsigned int)v.x, w1 = (unsigned int)v.y,
               w2 = (unsigned int)v.z, w3 = (unsigned int)v.w;
  union { unsigned int u; float f; } c;
  c.u = w0 << 16;         s[0] += c.f;
  c.u = w0 & 0xffff0000u; s[1] += c.f;
  c.u = w1 << 16;         s[2] += c.f;
  c.u = w1 & 0xffff0000u; s[3] += c.f;
  c.u = w2 << 16;         s[4] += c.f;
  c.u = w2 & 0xffff0000u; s[5] += c.f;
  c.u = w3 << 16;         s[6] += c.f;
  c.u = w3 & 0xffff0000u; s[7] += c.f;
}

static __device__ __forceinline__ void addbias8(float* s, const float* b) {
  f32x4 x0 = *reinterpret_cast<const f32x4*>(b);
  f32x4 x1 = *reinterpret_cast<const f32x4*>(b + 4);
#pragma unroll
  for (int i = 0; i < 4; ++i) { s[i] += x0[i]; s[4 + i] += x1[i]; }
}

// Stage A of per-column absmax: fused over all three (2048 x 6144) matrices,
// float4 loads, full occupancy. See R1/R2 notes.
__global__ __launch_bounds__(256) void colmax_k(const float* __restrict__ s0,
                                                const float* __restrict__ s1,
                                                const float* __restrict__ s2,
                                                unsigned int* __restrict__ cmax) {
  int b = blockIdx.x;
  int cg = b % 24;           // column group (256 cols)
  int rc = (b / 24) & 31;    // row chunk (64 rows)
  int mat = b / 768;         // which matrix
  const float* src = (mat == 0) ? s0 : (mat == 1) ? s1 : s2;
  int fc = threadIdx.x & 63;   // float4 column within group
  int r0 = threadIdx.x >> 6;   // 0..3
  const char* base = (const char*)src
      + ((size_t)(rc * 64 + r0) * G3 + cg * 256 + fc * 4) * 4;
  f32x4 m = {0.f, 0.f, 0.f, 0.f};
#pragma unroll
  for (int k = 0; k < 16; ++k) {
    f32x4 v = *reinterpret_cast<const f32x4*>(base + (size_t)k * (4 * G3 * 4));
#pragma unroll
    for (int i = 0; i < 4; ++i) m[i] = fmaxf(m[i], fabsf(v[i]));
  }
  __shared__ f32x4 red[256];
  red[threadIdx.x] = m;
  __syncthreads();
  if (threadIdx.x < 64) {
    int t = threadIdx.x;
    f32x4 a = red[t], b2 = red[t + 64], c2 = red[t + 128], d2 = red[t + 192];
    unsigned int* out = cmax + mat * G3 + cg * 256 + t * 4;
#pragma unroll
    for (int i = 0; i < 4; ++i) {
      float mm = fmaxf(fmaxf(a[i], b2[i]), fmaxf(c2[i], d2[i]));
      atomicMax(out + i, __float_as_uint(mm));
    }
  }
}

// Stage B: colmax (uint bits, stored in the QI block) -> fscale = m/127^2 and
// qinv = 127/m (in place). 72 blocks x 256 threads cover 3*6144 columns.
__global__ void colscale_fin_k(float* __restrict__ fs,
                               unsigned int* __restrict__ qinv) {
  int i = blockIdx.x * 256 + threadIdx.x;
  float m = __uint_as_float(qinv[i]);
  fs[i] = m * (1.f / 16129.f);
  reinterpret_cast<float*>(qinv)[i] = 127.f / m;
}

// fp32 (2048 x 6144) -> int8 MFMA-tiled (per-column scaled), all 3 matrices
// in one launch (9216 blocks). blockIdx/3072 picks the matrix.
__global__ __launch_bounds__(256) void convert_w_i8(const float* __restrict__ s0,
                                                    const float* __restrict__ s1,
                                                    const float* __restrict__ s2,
                                                    const float* __restrict__ qinv,
                                                    signed char* __restrict__ dst) {
  int mb = blockIdx.x / 3072;
  int tid = (blockIdx.x - mb * 3072) * 256 + threadIdx.x;   // 786432 groups/mat
  const float* src = (mb == 0) ? s0 : (mb == 1) ? s1 : s2;
  const float* qi_ = qinv + mb * G3;
  signed char* d_ = dst + (size_t)mb * 12582912;
  int gg = tid >> 18;
  int rem = tid & 262143;
  int ctc = rem >> 6;          // ct*32 + c
  int L = rem & 63;
  int ct = ctc >> 5, c = ctc & 31;
  int nl = L & 15, kq = L >> 4;
  int ocol = gg * 2048 + ct * 16 + nl;
  int kbase = c * 64 + kq * 16;
  float qi = qi_[ocol];
  union { signed char b[16]; int4 v; } o;
#pragma unroll
  for (int j = 0; j < 16; ++j) {
    int k = kbase + j;
    int q = (int)rintf(src[(size_t)k * G3 + ocol] * qi);
    o.b[j] = (signed char)q;
  }
  *reinterpret_cast<int4*>(d_ + (size_t)tid * 16) = o.v;
}

// Convert fp32 weight (ksrc x 6144, row-major) -> bf16 MFMA-tiled layout (W0K only).
__global__ void convert_w(const float* __restrict__ src, unsigned short* __restrict__ dst,
                          int ksrc, int kc_shift) {
  int tid = blockIdx.x * 256 + threadIdx.x;
  int nl = tid & 15;
  int kb = (tid >> 4) & 3;
  int kc_mask = (1 << kc_shift) - 1;
  int c  = (tid >> 6) & kc_mask;
  int ct = tid >> (6 + kc_shift);
  int col = ct * 16 + nl;
  int kbase = c * 32 + kb * 8;
  union { unsigned short u[8]; int4 v; } o;
#pragma unroll
  for (int j = 0; j < 8; ++j) {
    int k = kbase + j;
    float v = (k < ksrc) ? src[(size_t)k * G3 + col] : 0.f;
    o.u[j] = f2bf(v);
  }
  *reinterpret_cast<int4*>(dst + (size_t)tid * 8) = o.v;
}

// X[t][b][e] = bf16(emb[tokens[b][t]][e]), e padded to 128 with zeros.
__global__ void embed_k(const int* __restrict__ tokens, const float* __restrict__ emb,
                        unsigned short* __restrict__ X) {
  int idx = blockIdx.x * 256 + threadIdx.x;
  int e = idx & (EP - 1);
  int b = (idx >> 7) & (BB - 1);
  int t = idx >> 14;
  float v = 0.f;
  if (e < EE) {
    int tok = tokens[b * TT + t];
    v = emb[(size_t)tok * EE + e];
  }
  X[idx] = f2bf(v);
}

// Store one f32x4 acc plane as bf16: C/D layout col=lane&15, row=kq*4+reg.
static __device__ __forceinline__ void store_plane(
    unsigned short* __restrict__ G, const f32x4& a, int ct16, int mt8, int lane) {
  int col = ct16 * 16 + (lane & 15);
  int kq = lane >> 4;
#pragma unroll
  for (int r = 0; r < 4; ++r) {
    int m = mt8 * 16 + kq * 4 + r;
    G[(size_t)m * UU + col] = f2bf(a[r]);
  }
}

// Sharded grid barrier for exactly 768 co-resident blocks.
// bar[0..2047]: 64 shard counters (stride 32 uints = 128 B); bar[2048]: root.
// Monotone counters, no reset: after barrier #k, root == 64*k.
// __threadfence() (agent seq_cst) provides the cross-XCD L2 writeback /
// invalidate required by CDNA4 non-coherent per-XCD L2s (G16). Weights live
// in LDS, so the invalidate does not evict them.
static __device__ __forceinline__ void gbar(unsigned int* bar, int k) {
  __syncthreads();
  if (threadIdx.x == 0) {
    __threadfence();   // release: drain + write back dirty L2 to coherence point
    int s = blockIdx.x & 63;
    unsigned old = __hip_atomic_fetch_add(&bar[s * 32], 1u, __ATOMIC_RELAXED,
                                          __HIP_MEMORY_SCOPE_AGENT);
    if (((old + 1u) % 12u) == 0u)   // last of this shard's 12 blocks
      __hip_atomic_fetch_add(&bar[2048], 1u, __ATOMIC_RELAXED,
                             __HIP_MEMORY_SCOPE_AGENT);
    unsigned tgt = (unsigned)(64 * k);
    while (__hip_atomic_load(&bar[2048], __ATOMIC_RELAXED,
                             __HIP_MEMORY_SCOPE_AGENT) < tgt)
      __builtin_amdgcn_s_sleep(2);
    __threadfence();   // acquire: invalidate L1/L2 before reading others' data
  }
  __syncthreads();
}

// Persistent recurrent loop: 768 blocks x 256 threads, 3 blocks/CU
// (co-resident by construction: LDS 48 KB -> 3/CU, launch_bounds caps VGPR).
// Each block holds its 48 KB int8 weight tile (3 gates x 32 cols x K=512) in
// LDS for all 81 iterations — the 37.7 MB/step weight stream becomes a
// one-time load. Per iteration: GEMM phase (int8 MFMA from LDS) -> barrier ->
// gates phase (blocks [0,128): L0, [256,384): L1) -> barrier.
__global__ __launch_bounds__(256, 3) void rnn_loop(
    const unsigned short* __restrict__ X,
    const unsigned short* __restrict__ W0K,
    const signed char* __restrict__ QW0R, const signed char* __restrict__ QW1K,
    const signed char* __restrict__ QW1R,
    const float* __restrict__ FS0R, const float* __restrict__ FS1K,
    const float* __restrict__ FS1R,
    signed char* __restrict__ H0Q, signed char* __restrict__ H1Q,
    unsigned short* __restrict__ G0, unsigned short* __restrict__ G1I,
    unsigned short* __restrict__ G1R,
    const float* __restrict__ b0, const float* __restrict__ b1,
    float* __restrict__ H0F, float* __restrict__ H1F,
    unsigned int* __restrict__ bar) {
  int tu = blockIdx.x & 63;
  int kh = (blockIdx.x >> 6) & 3;
  int g  = blockIdx.x >> 8;
  int lane = threadIdx.x & 63;
  int wave = threadIdx.x >> 6;   // rows wave*32 .. +32
  int nl = lane & 15;
  int kq = lane >> 4;

  __shared__ unsigned char sbuf[49152];   // this block's persistent weight tile

  const signed char* Aq = (g == 2) ? H1Q : H0Q;
  const signed char* QW = (g == 0) ? QW0R : (g == 1) ? QW1K : QW1R;
  const float* FS = (g == 0) ? FS0R : (g == 1) ? FS1K : FS1R;
  unsigned short* Gout = (g == 0) ? G0 : (g == 1) ? G1I : G1R;

  // one-time LDS fill: slot = (kc*2+nt)*3+gg (kc 0..7), addr = slot*1024+l16*16
  {
    int t = threadIdx.x;
#pragma unroll
    for (int i = 0; i < 12; ++i) {
      int ss = i * 256 + t;
      int slot = ss >> 6, l16 = ss & 63;
      int gg = slot % 3, q = slot / 3;
      int nt = q & 1, kc = q >> 1;
      size_t off = (size_t)gg * 4194304
                 + (size_t)(((tu * 2 + nt) * 32 + kh * 8 + kc) * 64 + l16) * 16;
      *reinterpret_cast<int4*>(&sbuf[ss * 16]) =
          *reinterpret_cast<const int4*>(QW + off);
    }
  }
  __syncthreads();

  const signed char* ap[2];
#pragma unroll
  for (int mt = 0; mt < 2; ++mt)
    ap[mt] = Aq + (size_t)(wave * 32 + mt * 16 + nl) * UU + kq * 16;

  int gt = blockIdx.x * 256 + threadIdx.x;
  int bk = 1;

  for (int d = 0; d <= TT; ++d) {
    bool activeA = (g == 0) ? (d < TT) : (d >= 1);
    if (activeA) {
      i32x4 acc[2][2][3];   // [mt][nt][gate]
#pragma unroll
      for (int mt = 0; mt < 2; ++mt)
#pragma unroll
        for (int nt = 0; nt < 2; ++nt)
#pragma unroll
          for (int gg = 0; gg < 3; ++gg) acc[mt][nt][gg] = {0, 0, 0, 0};

      i32x4 a_cur[2], a_nxt[2];
#pragma unroll
      for (int mt = 0; mt < 2; ++mt)
        a_cur[mt] = *reinterpret_cast<const i32x4*>(ap[mt] + (size_t)(kh * 8) * 64);
#pragma unroll
      for (int kc = 0; kc < 8; ++kc) {
        if (kc < 7) {
#pragma unroll
          for (int mt = 0; mt < 2; ++mt)
            a_nxt[mt] = *reinterpret_cast<const i32x4*>(
                ap[mt] + (size_t)(kh * 8 + kc + 1) * 64);
        }
#pragma unroll
        for (int nt = 0; nt < 2; ++nt) {
#pragma unroll
          for (int gg = 0; gg < 3; ++gg) {
            i32x4 b = *reinterpret_cast<const i32x4*>(
                &sbuf[((kc * 2 + nt) * 3 + gg) * 1024 + lane * 16]);
#pragma unroll
            for (int mt = 0; mt < 2; ++mt)
              acc[mt][nt][gg] = __builtin_amdgcn_mfma_i32_16x16x64_i8(
                  a_cur[mt], b, acc[mt][nt][gg], 0, 0, 0);
          }
        }
#pragma unroll
        for (int mt = 0; mt < 2; ++mt) a_cur[mt] = a_nxt[mt];
      }

      // L0 input projection (bf16, K=128 padded), g==0 && kh==0 blocks
      f32x4 acci[2][2][2];   // [mt][nt][z/r]
      bool do_inp = (g == 0 && kh == 0);
      if (do_inp) {
#pragma unroll
        for (int nt = 0; nt < 2; ++nt) {
          const unsigned short* wp = W0K + (size_t)(tu * 2 + nt) * 4 * 512
                                   + (size_t)lane * 8;
#pragma unroll
          for (int mt = 0; mt < 2; ++mt) {
            const unsigned short* xp = X + (size_t)d * BB * EP
                + (size_t)(wave * 32 + mt * 16 + nl) * EP + kq * 8;
            f32x4 t0 = {0,0,0,0}, t1 = {0,0,0,0}, t2 = {0,0,0,0};
#pragma unroll
            for (int c = 0; c < 4; ++c) {
              bf16x8 a  = *reinterpret_cast<const bf16x8*>(xp + c * 32);
              bf16x8 w0 = *reinterpret_cast<const bf16x8*>(wp + (size_t)0 * (128 * 4 * 512) + c * 512);
              bf16x8 w1 = *reinterpret_cast<const bf16x8*>(wp + (size_t)1 * (128 * 4 * 512) + c * 512);
              bf16x8 w2 = *reinterpret_cast<const bf16x8*>(wp + (size_t)2 * (128 * 4 * 512) + c * 512);
              t0 = __builtin_amdgcn_mfma_f32_16x16x32_bf16(a, w0, t0, 0, 0, 0);
              t1 = __builtin_amdgcn_mfma_f32_16x16x32_bf16(a, w1, t1, 0, 0, 0);
              t2 = __builtin_amdgcn_mfma_f32_16x16x32_bf16(a, w2, t2, 0, 0, 0);
            }
            acci[mt][nt][0] = t0;
            acci[mt][nt][1] = t1;
            store_plane(G0 + (size_t)12 * PLANE, t2, tu * 2 + nt, wave * 2 + mt, lane);
          }
        }
      }

      // epilogue: dequantize + bf16 partial planes (plane = gate*4 + kh)
#pragma unroll
      for (int mt = 0; mt < 2; ++mt) {
#pragma unroll
        for (int nt = 0; nt < 2; ++nt) {
          int ct16 = tu * 2 + nt;
          int col = ct16 * 16 + nl;
          int mt8 = wave * 2 + mt;
          float fs0 = FS[0 * UU + col], fs1 = FS[1 * UU + col], fs2 = FS[2 * UU + col];
          f32x4 p0, p1, p2;
#pragma unroll
          for (int i = 0; i < 4; ++i) {
            p0[i] = (float)acc[mt][nt][0][i] * fs0;
            p1[i] = (float)acc[mt][nt][1][i] * fs1;
            p2[i] = (float)acc[mt][nt][2][i] * fs2;
          }
          if (do_inp) { p0 += acci[mt][nt][0]; p1 += acci[mt][nt][1]; }
          store_plane(Gout + (size_t)(0 + kh) * PLANE, p0, ct16, mt8, lane);
          store_plane(Gout + (size_t)(4 + kh) * PLANE, p1, ct16, mt8, lane);
          store_plane(Gout + (size_t)(8 + kh) * PLANE, p2, ct16, mt8, lane);
        }
      }
    }

    gbar(bar, bk++);   // G planes visible to gates blocks

    // gates phase: blocks [0,128) do L0 (h0(d)), blocks [256,384) do L1 (h1(d-1))
    if (blockIdx.x < 128) {
      if (d < TT) {
        int t = gt;                      // [0, 32768)
        size_t idx = (size_t)t * 8;
        int u = (int)(idx & (UU - 1));
        float zs[8] = {0,0,0,0,0,0,0,0}, rs[8] = {0,0,0,0,0,0,0,0};
        float hh[8] = {0,0,0,0,0,0,0,0}, ih[8] = {0,0,0,0,0,0,0,0};
#pragma unroll
        for (int p = 0; p < 4; ++p) {
          acc8(zs, G0 + (size_t)p * PLANE + idx);
          acc8(rs, G0 + (size_t)(4 + p) * PLANE + idx);
          acc8(hh, G0 + (size_t)(8 + p) * PLANE + idx);
        }
        acc8(ih, G0 + (size_t)12 * PLANE + idx);
        addbias8(zs, b0 + u);          addbias8(zs, b0 + G3 + u);
        addbias8(rs, b0 + UU + u);     addbias8(rs, b0 + G3 + UU + u);
        addbias8(ih, b0 + 2 * UU + u);
        addbias8(hh, b0 + G3 + 2 * UU + u);
        f32x4 h0 = *reinterpret_cast<const f32x4*>(H0F + idx);
        f32x4 h1 = *reinterpret_cast<const f32x4*>(H0F + idx + 4);
        float hold[8] = {h0[0], h0[1], h0[2], h0[3], h1[0], h1[1], h1[2], h1[3]};
        float hn[8];
#pragma unroll
        for (int i = 0; i < 8; ++i) {
          float z = sigf(zs[i]), r = sigf(rs[i]);
          float cand = tanhfast(ih[i] + r * hh[i]);
          hn[i] = z * hold[i] + (1.f - z) * cand;
        }
        unsigned int qa = 0, qb = 0;
#pragma unroll
        for (int i = 0; i < 4; ++i) {
          qa |= ((unsigned int)((int)rintf(hn[i] * 127.f) & 0xff)) << (8 * i);
          qb |= ((unsigned int)((int)rintf(hn[4 + i] * 127.f) & 0xff)) << (8 * i);
        }
        *reinterpret_cast<f32x4*>(H0F + idx)     = f32x4{hn[0], hn[1], hn[2], hn[3]};
        *reinterpret_cast<f32x4*>(H0F + idx + 4) = f32x4{hn[4], hn[5], hn[6], hn[7]};
        *reinterpret_cast<uint2*>(H0Q + idx) = make_uint2(qa, qb);
      }
    } else if (blockIdx.x >= 256 && blockIdx.x < 384) {
      if (d >= 1) {
        int t = gt - 65536;              // [0, 32768)
        size_t idx = (size_t)t * 8;
        int u = (int)(idx & (UU - 1));
        float iz[8] = {0,0,0,0,0,0,0,0}, ir[8] = {0,0,0,0,0,0,0,0}, ih[8] = {0,0,0,0,0,0,0,0};
        float hz[8] = {0,0,0,0,0,0,0,0}, hr[8] = {0,0,0,0,0,0,0,0}, hh[8] = {0,0,0,0,0,0,0,0};
#pragma unroll
        for (int p = 0; p < 4; ++p) {
          acc8(iz, G1I + (size_t)p * PLANE + idx);
          acc8(ir, G1I + (size_t)(4 + p) * PLANE + idx);
          acc8(ih, G1I + (size_t)(8 + p) * PLANE + idx);
          acc8(hz, G1R + (size_t)p * PLANE + idx);
          acc8(hr, G1R + (size_t)(4 + p) * PLANE + idx);
          acc8(hh, G1R + (size_t)(8 + p) * PLANE + idx);
        }
        addbias8(iz, b1 + u);           addbias8(hz, b1 + G3 + u);
        addbias8(ir, b1 + UU + u);      addbias8(hr, b1 + G3 + UU + u);
        addbias8(ih, b1 + 2 * UU + u);  addbias8(hh, b1 + G3 + 2 * UU + u);
        f32x4 h0 = *reinterpret_cast<const f32x4*>(H1F + idx);
        f32x4 h1 = *reinterpret_cast<const f32x4*>(H1F + idx + 4);
        float hold[8] = {h0[0], h0[1], h0[2], h0[3], h1[0], h1[1], h1[2], h1[3]};
        float hn[8];
#pragma unroll
        for (int i = 0; i < 8; ++i) {
          float z = sigf(iz[i] + hz[i]), r = sigf(ir[i] + hr[i]);
          float cand = tanhfast(ih[i] + r * hh[i]);
          hn[i] = z * hold[i] + (1.f - z) * cand;
        }
        unsigned int qa = 0, qb = 0;
#pragma unroll
        for (int i = 0; i < 4; ++i) {
          qa |= ((unsigned int)((int)rintf(hn[i] * 127.f) & 0xff)) << (8 * i);
          qb |= ((unsigned int)((int)rintf(hn[4 + i] * 127.f) & 0xff)) << (8 * i);
        }
        *reinterpret_cast<f32x4*>(H1F + idx)     = f32x4{hn[0], hn[1], hn[2], hn[3]};
        *reinterpret_cast<f32x4*>(H1F + idx + 4) = f32x4{hn[4], hn[5], hn[6], hn[7]};
        *reinterpret_cast<uint2*>(H1Q + idx) = make_uint2(qa, qb);
      }
    }

    gbar(bar, bk++);   // H state visible to next iteration's GEMM blocks
  }
}

// logits = sigmoid(h1 @ wout + bout): 128 blocks x 64 threads, one row each.
__global__ void out_k(const float* __restrict__ h1, const float* __restrict__ wout,
                      const float* __restrict__ bout, float* __restrict__ out) {
  int row = blockIdx.x;
  int lane = threadIdx.x;
  float s = 0.f;
  for (int i = lane; i < UU; i += 64) s += h1[(size_t)row * UU + i] * wout[i];
#pragma unroll
  for (int off = 32; off > 0; off >>= 1) s += __shfl_down(s, off);
  if (lane == 0) out[row] = 1.f / (1.f + __expf(-(s + bout[0])));
}

extern "C" void kernel_launch(void* const* d_in, const int* in_sizes, int n_in,
                              void* d_out, int out_size, void* d_ws, size_t ws_size,
                              hipStream_t stream) {
  const int*   tokens = (const int*)  d_in[0];
  const float* emb    = (const float*)d_in[1];
  const float* k0     = (const float*)d_in[2];
  const float* r0     = (const float*)d_in[3];
  const float* b0     = (const float*)d_in[4];
  const float* k1     = (const float*)d_in[5];
  const float* r1     = (const float*)d_in[6];
  const float* b1     = (const float*)d_in[7];
  const float* wout   = (const float*)d_in[8];
  const float* bout   = (const float*)d_in[9];
  float* out = (float*)d_out;

  char* ws = (char*)d_ws;
  unsigned short* W0K = (unsigned short*)(ws + 0);           //  1.5 MB bf16 tiled
  signed char* QW0R   = (signed char*)(ws + 1572864);        // 12.6 MB int8 tiled
  signed char* QW1K   = (signed char*)(ws + 14155776);       // 12.6 MB
  signed char* QW1R   = (signed char*)(ws + 26738688);       // 12.6 MB
  float* FS0R         = (float*)(ws + 39321600);             // 24 KB dequant scales
  float* FS1K         = (float*)(ws + 39346176);
  float* FS1R         = (float*)(ws + 39370752);
  float* QI0R         = (float*)(ws + 39395328);             // 24 KB quant inv-scales
  float* QI1K         = (float*)(ws + 39419904);
  float* QI1R         = (float*)(ws + 39444480);
  unsigned short* X   = (unsigned short*)(ws + 39469056);    //  2.6 MB bf16
  float* H0F          = (float*)(ws + 42090496);             //  1 MB fp32 state
  float* H1F          = (float*)(ws + 43139072);             //  1 MB
  signed char* H0Q    = (signed char*)(ws + 44187648);       //  0.25 MB int8 state
  signed char* H1Q    = (signed char*)(ws + 44449792);       //  0.25 MB
  unsigned short* G0  = (unsigned short*)(ws + 44711936);    // 13 bf16 planes (6.5 MB)
  unsigned short* G1I = (unsigned short*)(ws + 51527680);    // 12 bf16 planes (6 MB)
  unsigned short* G1R = (unsigned short*)(ws + 57819136);    // 12 bf16 planes (6 MB)
  // barrier counters reuse the QI region (free after convert_w_i8)
  unsigned int* BAR   = (unsigned int*)QI0R;                 // 8196 B used
  // total ws use: 64,110,592 bytes

  // zero h state (H0F, H1F, H0Q, H1Q contiguous): 2.5 MiB
  hipMemsetAsync(ws + 42090496, 0, 2621440, stream);
  // zero colmax accumulators (QI0R/QI1K/QI1R contiguous, 3 x 24 KB)
  hipMemsetAsync(ws + 39395328, 0, 73728, stream);

  // per-column absmax: fused two-stage reduction at full occupancy,
  // then finalize scales.
  colmax_k<<<2304, 256, 0, stream>>>(r0, k1, r1, (unsigned int*)QI0R);
  colscale_fin_k<<<72, 256, 0, stream>>>(FS0R, (unsigned int*)QI0R);

  // int8 tiled conversion, all three matrices in one launch
  convert_w_i8<<<9216, 256, 0, stream>>>(r0, k1, r1, QI0R, QW0R);

  // L0 input-proj weights stay bf16 (tiny, K=128 padded)
  convert_w<<<384, 256, 0, stream>>>(k0, W0K, 100, 2);

  // embedding gather (time-major, padded)
  embed_k<<<5120, 256, 0, stream>>>(tokens, emb, X);

  // zero barrier counters (QI region is dead after convert_w_i8)
  hipMemsetAsync(ws + 39395328, 0, 12288, stream);

  // persistent recurrent loop: all 81 steps in one 768-block dispatch,
  // weights LDS-resident, manual grid barriers between phases.
  rnn_loop<<<768, 256, 0, stream>>>(X, W0K, QW0R, QW1K, QW1R,
                                    FS0R, FS1K, FS1R, H0Q, H1Q,
                                    G0, G1I, G1R, b0, b1, H0F, H1F, BAR);

  out_k<<<128, 64, 0, stream>>>(H1F, wout, bout, out);
}

// Round 4
// 2010.519 us; speedup vs baseline: 5.2199x; 5.2199x over previous
//
#include <hip/hip_runtime.h>
#include <cstdint>
#include <cstddef>

#define BB 128    // batch
#define TT 80     // seq
#define EE 100    // emb dim
#define EP 128    // padded emb dim
#define UU 2048   // units
#define G3 6144   // 3*UU
#define PLANE (BB * UU)   // 262144 elements (one [batch][unit] plane)

typedef __bf16 bf16x8 __attribute__((ext_vector_type(8)));
typedef float f32x4 __attribute__((ext_vector_type(4)));
typedef int   i32x4 __attribute__((ext_vector_type(4)));

static __device__ __forceinline__ unsigned short f2bf(float x) {
  union { float f; unsigned int u; } a; a.f = x;
  unsigned int r = a.u + 0x7fffu + ((a.u >> 16) & 1u);  // RNE
  return (unsigned short)(r >> 16);
}

static __device__ __forceinline__ float sigf(float x) {
  return 1.f / (1.f + __expf(-x));
}
static __device__ __forceinline__ float tanhfast(float x) {
  return 1.f - 2.f / (__expf(2.f * x) + 1.f);
}

// Stage A of per-column absmax: fused over all three (2048 x 6144) matrices,
// float4 loads, full occupancy (R2 version, 48 us).
__global__ __launch_bounds__(256) void colmax_k(const float* __restrict__ s0,
                                                const float* __restrict__ s1,
                                                const float* __restrict__ s2,
                                                unsigned int* __restrict__ cmax) {
  int b = blockIdx.x;
  int cg = b % 24;           // column group (256 cols)
  int rc = (b / 24) & 31;    // row chunk (64 rows)
  int mat = b / 768;         // which matrix
  const float* src = (mat == 0) ? s0 : (mat == 1) ? s1 : s2;
  int fc = threadIdx.x & 63;   // float4 column within group
  int r0 = threadIdx.x >> 6;   // 0..3
  const char* base = (const char*)src
      + ((size_t)(rc * 64 + r0) * G3 + cg * 256 + fc * 4) * 4;
  f32x4 m = {0.f, 0.f, 0.f, 0.f};
#pragma unroll
  for (int k = 0; k < 16; ++k) {
    f32x4 v = *reinterpret_cast<const f32x4*>(base + (size_t)k * (4 * G3 * 4));
#pragma unroll
    for (int i = 0; i < 4; ++i) m[i] = fmaxf(m[i], fabsf(v[i]));
  }
  __shared__ f32x4 red[256];
  red[threadIdx.x] = m;
  __syncthreads();
  if (threadIdx.x < 64) {
    int t = threadIdx.x;
    f32x4 a = red[t], b2 = red[t + 64], c2 = red[t + 128], d2 = red[t + 192];
    unsigned int* out = cmax + mat * G3 + cg * 256 + t * 4;
#pragma unroll
    for (int i = 0; i < 4; ++i) {
      float mm = fmaxf(fmaxf(a[i], b2[i]), fmaxf(c2[i], d2[i]));
      atomicMax(out + i, __float_as_uint(mm));
    }
  }
}

// Stage B: colmax bits -> fscale = m/127^2 and qinv = 127/m (in place).
__global__ void colscale_fin_k(float* __restrict__ fs,
                               unsigned int* __restrict__ qinv) {
  int i = blockIdx.x * 256 + threadIdx.x;
  float m = __uint_as_float(qinv[i]);
  fs[i] = m * (1.f / 16129.f);
  reinterpret_cast<float*>(qinv)[i] = 127.f / m;
}

// fp32 (2048 x 6144) -> int8 MFMA-tiled (per-column scaled), all 3 matrices.
// lane L of chunk c holds B[k = c*64 + (L>>4)*16 + j][col = ct*16 + (L&15)].
__global__ __launch_bounds__(256) void convert_w_i8(const float* __restrict__ s0,
                                                    const float* __restrict__ s1,
                                                    const float* __restrict__ s2,
                                                    const float* __restrict__ qinv,
                                                    signed char* __restrict__ dst) {
  int mb = blockIdx.x / 3072;
  int tid = (blockIdx.x - mb * 3072) * 256 + threadIdx.x;   // 786432 groups/mat
  const float* src = (mb == 0) ? s0 : (mb == 1) ? s1 : s2;
  const float* qi_ = qinv + mb * G3;
  signed char* d_ = dst + (size_t)mb * 12582912;
  int gg = tid >> 18;
  int rem = tid & 262143;
  int ctc = rem >> 6;          // ct*32 + c
  int L = rem & 63;
  int ct = ctc >> 5, c = ctc & 31;
  int nl = L & 15, kq = L >> 4;
  int ocol = gg * 2048 + ct * 16 + nl;
  int kbase = c * 64 + kq * 16;
  float qi = qi_[ocol];
  union { signed char b[16]; int4 v; } o;
#pragma unroll
  for (int j = 0; j < 16; ++j) {
    int k = kbase + j;
    int q = (int)rintf(src[(size_t)k * G3 + ocol] * qi);
    o.b[j] = (signed char)q;
  }
  *reinterpret_cast<int4*>(d_ + (size_t)tid * 16) = o.v;
}

// fp32 (ksrc x 6144) -> bf16 MFMA-tiled layout (W0K only, K padded to 128).
__global__ void convert_w(const float* __restrict__ src, unsigned short* __restrict__ dst,
                          int ksrc, int kc_shift) {
  int tid = blockIdx.x * 256 + threadIdx.x;
  int nl = tid & 15;
  int kb = (tid >> 4) & 3;
  int kc_mask = (1 << kc_shift) - 1;
  int c  = (tid >> 6) & kc_mask;
  int ct = tid >> (6 + kc_shift);
  int col = ct * 16 + nl;
  int kbase = c * 32 + kb * 8;
  union { unsigned short u[8]; int4 v; } o;
#pragma unroll
  for (int j = 0; j < 8; ++j) {
    int k = kbase + j;
    float v = (k < ksrc) ? src[(size_t)k * G3 + col] : 0.f;
    o.u[j] = f2bf(v);
  }
  *reinterpret_cast<int4*>(dst + (size_t)tid * 8) = o.v;
}

// X[t][b][e] = bf16(emb[tokens[b][t]][e]), e padded to 128 with zeros.
__global__ void embed_k(const int* __restrict__ tokens, const float* __restrict__ emb,
                        unsigned short* __restrict__ X) {
  int idx = blockIdx.x * 256 + threadIdx.x;
  int e = idx & (EP - 1);
  int b = (idx >> 7) & (BB - 1);
  int t = idx >> 14;
  float v = 0.f;
  if (e < EE) {
    int tok = tokens[b * TT + t];
    v = emb[(size_t)tok * EE + e];
  }
  X[idx] = f2bf(v);
}

// Fused step dispatch d (0..80), 256 blocks x 256 threads, full-K GEMM +
// inline gate math. No intermediate G planes.
//   blocks [0,128)  (type A): h0(d) for units [blk*16, +16): 3-gate r0 GEMM
//     (K=2048 int8) + x_d@k0 input proj (K=128 bf16) + gates -> H0F/H0Q.
//   blocks [128,256) (type B): h1(d-1) for units: 6 slots = {k1,r1} x 3 gates,
//     K=2048 int8 with two A operands (h0(d-1), h1(d-2)) + gates -> H1F/H1Q.
// Quantized state parity double-buffer: h(s) lives in buf[s&1]; readers use
// the previous-parity buffer, so there is no intra-dispatch RAW race, and
// kernel boundaries provide cross-XCD visibility.
__global__ __launch_bounds__(256) void step_fused(
    int d,
    const unsigned short* __restrict__ X,
    const unsigned short* __restrict__ W0K,
    const signed char* __restrict__ QW0R, const signed char* __restrict__ QW1K,
    const float* __restrict__ FS0R, const float* __restrict__ FS1K,
    const float* __restrict__ FS1R,
    const float* __restrict__ b0, const float* __restrict__ b1,
    float* __restrict__ H0F, float* __restrict__ H1F,
    signed char* __restrict__ H0Q, signed char* __restrict__ H1Q) {
  int blk = blockIdx.x;
  bool tA = blk < 128;
  if (tA) { if (d >= TT) return; }
  else    { if (d < 1)   return; }
  int ct16 = tA ? blk : blk - 128;
  int lane = threadIdx.x & 63;
  int wave = threadIdx.x >> 6;
  int nl = lane & 15, kq = lane >> 4;
  int u = ct16 * 16 + nl;

  __shared__ unsigned char sbuf[2][24576];   // double-buffered weight windows

  const signed char* AqI = H0Q + (size_t)((d + 1) & 1) * PLANE;  // h0(d-1)
  const signed char* AqH = H1Q + (size_t)(d & 1) * PLANE;        // h1(d-2)

  const signed char* apI[2];
  const signed char* apH[2];
#pragma unroll
  for (int mt = 0; mt < 2; ++mt) {
    int row = wave * 32 + mt * 16 + nl;
    apI[mt] = AqI + (size_t)row * UU + kq * 16;
    apH[mt] = AqH + (size_t)row * UU + kq * 16;
  }

  // staging map. LDS byte = ss*16 (ss = i*256 + tid) = wslot*1024 + lane*16.
  //  type A: wslot = kcw*3 + gg   (kcw 0..7, window = 8 K-chunks = 24 KB)
  //  type B: wslot = kcw*6 + mat*3 + gg (kcw 0..3, window = 4 K-chunks)
  // QW1R = QW1K + 12582912 by construction (mat folded into offset).
  const signed char* QWB = tA ? QW0R : QW1K;
  int woff[6];
  int soff0 = threadIdx.x * 16;
  {
    int t = threadIdx.x;
#pragma unroll
    for (int i = 0; i < 6; ++i) {
      int ss = i * 256 + t;
      int wslot = ss >> 6, l16 = ss & 63;
      int off;
      if (tA) {
        int kcw = wslot / 3, gg = wslot - kcw * 3;
        off = gg * 4194304 + (ct16 * 32 + kcw) * 1024 + l16 * 16;
      } else {
        int kcw = wslot / 6, rem = wslot - kcw * 6;
        int mat = rem / 3, gg = rem - mat * 3;
        off = mat * 12582912 + gg * 4194304 + (ct16 * 32 + kcw) * 1024 + l16 * 16;
      }
      woff[i] = off;
    }
  }
  // prologue: window 0
  {
    int4 v[6];
#pragma unroll
    for (int i = 0; i < 6; ++i)
      v[i] = *reinterpret_cast<const int4*>(QWB + (size_t)woff[i]);
#pragma unroll
    for (int i = 0; i < 6; ++i)
      *reinterpret_cast<int4*>(&sbuf[0][soff0 + i * 4096]) = v[i];
  }
  __syncthreads();

  if (tA) {
    // ---- type A: L0, 3 slots, 4 windows of 8 K-chunks ----
    i32x4 acc[3][2];
#pragma unroll
    for (int gg = 0; gg < 3; ++gg)
#pragma unroll
      for (int mt = 0; mt < 2; ++mt) acc[gg][mt] = {0, 0, 0, 0};

    i32x4 aI[2], nI[2];
#pragma unroll
    for (int mt = 0; mt < 2; ++mt)
      aI[mt] = *reinterpret_cast<const i32x4*>(apI[mt]);

#pragma unroll
    for (int w = 0; w < 4; ++w) {
      int4 v[6];
      if (w < 3) {
#pragma unroll
        for (int i = 0; i < 6; ++i)
          v[i] = *reinterpret_cast<const int4*>(QWB + (size_t)woff[i] + (w + 1) * 8192);
      }
#pragma unroll
      for (int kcw = 0; kcw < 8; ++kcw) {
        int kc = w * 8 + kcw;
        if (kc < 31) {
#pragma unroll
          for (int mt = 0; mt < 2; ++mt)
            nI[mt] = *reinterpret_cast<const i32x4*>(apI[mt] + (size_t)(kc + 1) * 64);
        }
#pragma unroll
        for (int gg = 0; gg < 3; ++gg) {
          i32x4 bw = *reinterpret_cast<const i32x4*>(
              &sbuf[w & 1][(kcw * 3 + gg) * 1024 + lane * 16]);
#pragma unroll
          for (int mt = 0; mt < 2; ++mt)
            acc[gg][mt] = __builtin_amdgcn_mfma_i32_16x16x64_i8(
                aI[mt], bw, acc[gg][mt], 0, 0, 0);
        }
        if (kc < 31) {
#pragma unroll
          for (int mt = 0; mt < 2; ++mt) aI[mt] = nI[mt];
        }
      }
      if (w < 3) {
#pragma unroll
        for (int i = 0; i < 6; ++i)
          *reinterpret_cast<int4*>(&sbuf[(w + 1) & 1][soff0 + i * 4096]) = v[i];
        __syncthreads();
      }
    }

    // input projection x_d @ k0 (bf16, K=128 padded): iz, ir, ih
    f32x4 ai[2][3];
    const unsigned short* wp = W0K + (size_t)ct16 * 2048 + (size_t)lane * 8;
#pragma unroll
    for (int mt = 0; mt < 2; ++mt) {
      const unsigned short* xp = X + (size_t)d * BB * EP
                               + (size_t)(wave * 32 + mt * 16 + nl) * EP + kq * 8;
      f32x4 t0 = {0,0,0,0}, t1 = {0,0,0,0}, t2 = {0,0,0,0};
#pragma unroll
      for (int c = 0; c < 4; ++c) {
        bf16x8 a  = *reinterpret_cast<const bf16x8*>(xp + c * 32);
        bf16x8 w0 = *reinterpret_cast<const bf16x8*>(wp + (size_t)0 * 262144 + c * 512);
        bf16x8 w1 = *reinterpret_cast<const bf16x8*>(wp + (size_t)1 * 262144 + c * 512);
        bf16x8 w2 = *reinterpret_cast<const bf16x8*>(wp + (size_t)2 * 262144 + c * 512);
        t0 = __builtin_amdgcn_mfma_f32_16x16x32_bf16(a, w0, t0, 0, 0, 0);
        t1 = __builtin_amdgcn_mfma_f32_16x16x32_bf16(a, w1, t1, 0, 0, 0);
        t2 = __builtin_amdgcn_mfma_f32_16x16x32_bf16(a, w2, t2, 0, 0, 0);
      }
      ai[mt][0] = t0; ai[mt][1] = t1; ai[mt][2] = t2;
    }

    // gates + state update for h0(d)
    float fsz = FS0R[u], fsr = FS0R[UU + u], fsh = FS0R[2 * UU + u];
    float bz  = b0[u] + b0[G3 + u];
    float br  = b0[UU + u] + b0[G3 + UU + u];
    float bih = b0[2 * UU + u];
    float bhh = b0[G3 + 2 * UU + u];
    signed char* H0Qw = H0Q + (size_t)(d & 1) * PLANE;
#pragma unroll
    for (int mt = 0; mt < 2; ++mt) {
      int m0 = wave * 32 + mt * 16 + kq * 4;
#pragma unroll
      for (int rr = 0; rr < 4; ++rr) {
        float hz = (float)acc[0][mt][rr] * fsz;
        float hr = (float)acc[1][mt][rr] * fsr;
        float hh = (float)acc[2][mt][rr] * fsh + bhh;
        float z    = sigf(ai[mt][0][rr] + hz + bz);
        float rg   = sigf(ai[mt][1][rr] + hr + br);
        float cand = tanhfast(ai[mt][2][rr] + bih + rg * hh);
        size_t o = (size_t)(m0 + rr) * UU + u;
        float hold = H0F[o];
        float hn = z * hold + (1.f - z) * cand;
        H0F[o] = hn;
        H0Qw[o] = (signed char)(int)rintf(hn * 127.f);
      }
    }
  } else {
    // ---- type B: L1, 6 slots (k1 x 3, r1 x 3), 8 windows of 4 K-chunks ----
    i32x4 acc[6][2];
#pragma unroll
    for (int s = 0; s < 6; ++s)
#pragma unroll
      for (int mt = 0; mt < 2; ++mt) acc[s][mt] = {0, 0, 0, 0};

    i32x4 aI[2], aH[2], nI[2], nH[2];
#pragma unroll
    for (int mt = 0; mt < 2; ++mt) {
      aI[mt] = *reinterpret_cast<const i32x4*>(apI[mt]);
      aH[mt] = *reinterpret_cast<const i32x4*>(apH[mt]);
    }

#pragma unroll
    for (int w = 0; w < 8; ++w) {
      int4 v[6];
      if (w < 7) {
#pragma unroll
        for (int i = 0; i < 6; ++i)
          v[i] = *reinterpret_cast<const int4*>(QWB + (size_t)woff[i] + (w + 1) * 4096);
      }
#pragma unroll
      for (int kcw = 0; kcw < 4; ++kcw) {
        int kc = w * 4 + kcw;
        if (kc < 31) {
#pragma unroll
          for (int mt = 0; mt < 2; ++mt) {
            nI[mt] = *reinterpret_cast<const i32x4*>(apI[mt] + (size_t)(kc + 1) * 64);
            nH[mt] = *reinterpret_cast<const i32x4*>(apH[mt] + (size_t)(kc + 1) * 64);
          }
        }
#pragma unroll
        for (int s = 0; s < 6; ++s) {
          i32x4 bw = *reinterpret_cast<const i32x4*>(
              &sbuf[w & 1][(kcw * 6 + s) * 1024 + lane * 16]);
#pragma unroll
          for (int mt = 0; mt < 2; ++mt)
            acc[s][mt] = __builtin_amdgcn_mfma_i32_16x16x64_i8(
                (s < 3) ? aI[mt] : aH[mt], bw, acc[s][mt], 0, 0, 0);
        }
        if (kc < 31) {
#pragma unroll
          for (int mt = 0; mt < 2; ++mt) { aI[mt] = nI[mt]; aH[mt] = nH[mt]; }
        }
      }
      if (w < 7) {
#pragma unroll
        for (int i = 0; i < 6; ++i)
          *reinterpret_cast<int4*>(&sbuf[(w + 1) & 1][soff0 + i * 4096]) = v[i];
        __syncthreads();
      }
    }

    // gates + state update for h1(d-1)
    float fiz = FS1K[u], fir = FS1K[UU + u], fih = FS1K[2 * UU + u];
    float fhz = FS1R[u], fhr = FS1R[UU + u], fhh = FS1R[2 * UU + u];
    float bz  = b1[u] + b1[G3 + u];
    float br  = b1[UU + u] + b1[G3 + UU + u];
    float bih = b1[2 * UU + u];
    float bhh = b1[G3 + 2 * UU + u];
    signed char* H1Qw = H1Q + (size_t)((d + 1) & 1) * PLANE;
#pragma unroll
    for (int mt = 0; mt < 2; ++mt) {
      int m0 = wave * 32 + mt * 16 + kq * 4;
#pragma unroll
      for (int rr = 0; rr < 4; ++rr) {
        float iz  = (float)acc[0][mt][rr] * fiz;
        float ir  = (float)acc[1][mt][rr] * fir;
        float ihv = (float)acc[2][mt][rr] * fih;
        float hz  = (float)acc[3][mt][rr] * fhz;
        float hr  = (float)acc[4][mt][rr] * fhr;
        float hhv = (float)acc[5][mt][rr] * fhh + bhh;
        float z    = sigf(iz + hz + bz);
        float rg   = sigf(ir + hr + br);
        float cand = tanhfast(ihv + bih + rg * hhv);
        size_t o = (size_t)(m0 + rr) * UU + u;
        float hold = H1F[o];
        float hn = z * hold + (1.f - z) * cand;
        H1F[o] = hn;
        H1Qw[o] = (signed char)(int)rintf(hn * 127.f);
      }
    }
  }
}

// logits = sigmoid(h1 @ wout + bout): 128 blocks x 64 threads, one row each.
__global__ void out_k(const float* __restrict__ h1, const float* __restrict__ wout,
                      const float* __restrict__ bout, float* __restrict__ out) {
  int row = blockIdx.x;
  int lane = threadIdx.x;
  float s = 0.f;
  for (int i = lane; i < UU; i += 64) s += h1[(size_t)row * UU + i] * wout[i];
#pragma unroll
  for (int off = 32; off > 0; off >>= 1) s += __shfl_down(s, off);
  if (lane == 0) out[row] = 1.f / (1.f + __expf(-(s + bout[0])));
}

extern "C" void kernel_launch(void* const* d_in, const int* in_sizes, int n_in,
                              void* d_out, int out_size, void* d_ws, size_t ws_size,
                              hipStream_t stream) {
  const int*   tokens = (const int*)  d_in[0];
  const float* emb    = (const float*)d_in[1];
  const float* k0     = (const float*)d_in[2];
  const float* r0     = (const float*)d_in[3];
  const float* b0     = (const float*)d_in[4];
  const float* k1     = (const float*)d_in[5];
  const float* r1     = (const float*)d_in[6];
  const float* b1     = (const float*)d_in[7];
  const float* wout   = (const float*)d_in[8];
  const float* bout   = (const float*)d_in[9];
  float* out = (float*)d_out;

  char* ws = (char*)d_ws;
  unsigned short* W0K = (unsigned short*)(ws + 0);           //  1.5 MB bf16 tiled
  signed char* QW0R   = (signed char*)(ws + 1572864);        // 12.6 MB int8 tiled
  signed char* QW1K   = (signed char*)(ws + 14155776);       // 12.6 MB
  signed char* QW1R   = (signed char*)(ws + 26738688);       // 12.6 MB (= QW1K + 12582912)
  float* FS0R         = (float*)(ws + 39321600);             // 24 KB dequant scales
  float* FS1K         = (float*)(ws + 39346176);
  float* FS1R         = (float*)(ws + 39370752);
  float* QI0R         = (float*)(ws + 39395328);             // 3 x 24 KB quant inv-scales
  unsigned short* X   = (unsigned short*)(ws + 39469056);    //  2.6 MB bf16
  float* H0F          = (float*)(ws + 42090496);             //  1 MB fp32 state
  float* H1F          = (float*)(ws + 43139072);             //  1 MB
  signed char* H0Q    = (signed char*)(ws + 44187648);       //  2 x 256 KB int8 state (parity)
  signed char* H1Q    = (signed char*)(ws + 44711936);       //  2 x 256 KB
  // total ws use: 45,236,224 bytes
  (void)QW1R;

  // zero state (H0F, H1F, H0Q[2], H1Q[2] contiguous): 3 MiB
  hipMemsetAsync(ws + 42090496, 0, 3145728, stream);
  // zero colmax accumulators (3 x 24 KB)
  hipMemsetAsync(ws + 39395328, 0, 73728, stream);

  // per-column absmax + scale finalize
  colmax_k<<<2304, 256, 0, stream>>>(r0, k1, r1, (unsigned int*)QI0R);
  colscale_fin_k<<<72, 256, 0, stream>>>(FS0R, (unsigned int*)QI0R);

  // int8 tiled conversion, all three matrices in one launch
  convert_w_i8<<<9216, 256, 0, stream>>>(r0, k1, r1, QI0R, QW0R);

  // L0 input-proj weights stay bf16 (tiny, K=128 padded)
  convert_w<<<384, 256, 0, stream>>>(k0, W0K, 100, 2);

  // embedding gather (time-major, padded)
  embed_k<<<5120, 256, 0, stream>>>(tokens, emb, X);

  // 81 fused step dispatches: d computes h0(d) and h1(d-1) in one kernel
  for (int d = 0; d <= TT; ++d) {
    step_fused<<<256, 256, 0, stream>>>(d, X, W0K, QW0R, QW1K,
                                        FS0R, FS1K, FS1R, b0, b1,
                                        H0F, H1F, H0Q, H1Q);
  }

  out_k<<<128, 64, 0, stream>>>(H1F, wout, bout, out);
}

// Round 5
// 1996.923 us; speedup vs baseline: 5.2554x; 1.0068x over previous
//
#include <hip/hip_runtime.h>
#include <cstdint>
#include <cstddef>

#define BB 128    // batch
#define TT 80     // seq
#define EE 100    // emb dim
#define EP 128    // padded emb dim
#define UU 2048   // units
#define G3 6144   // 3*UU
#define PLANE (BB * UU)   // 262144 elements (one [batch][unit] plane)

typedef __bf16 bf16x8 __attribute__((ext_vector_type(8)));
typedef float f32x4 __attribute__((ext_vector_type(4)));
typedef int   i32x4 __attribute__((ext_vector_type(4)));

static __device__ __forceinline__ unsigned short f2bf(float x) {
  union { float f; unsigned int u; } a; a.f = x;
  unsigned int r = a.u + 0x7fffu + ((a.u >> 16) & 1u);  // RNE
  return (unsigned short)(r >> 16);
}

static __device__ __forceinline__ float sigf(float x) {
  return 1.f / (1.f + __expf(-x));
}
static __device__ __forceinline__ float tanhfast(float x) {
  return 1.f - 2.f / (__expf(2.f * x) + 1.f);
}

// Stage A of per-column absmax: fused over all three (2048 x 6144) matrices,
// float4 loads, full occupancy (R2 version, 48 us).
__global__ __launch_bounds__(256) void colmax_k(const float* __restrict__ s0,
                                                const float* __restrict__ s1,
                                                const float* __restrict__ s2,
                                                unsigned int* __restrict__ cmax) {
  int b = blockIdx.x;
  int cg = b % 24;           // column group (256 cols)
  int rc = (b / 24) & 31;    // row chunk (64 rows)
  int mat = b / 768;         // which matrix
  const float* src = (mat == 0) ? s0 : (mat == 1) ? s1 : s2;
  int fc = threadIdx.x & 63;   // float4 column within group
  int r0 = threadIdx.x >> 6;   // 0..3
  const char* base = (const char*)src
      + ((size_t)(rc * 64 + r0) * G3 + cg * 256 + fc * 4) * 4;
  f32x4 m = {0.f, 0.f, 0.f, 0.f};
#pragma unroll
  for (int k = 0; k < 16; ++k) {
    f32x4 v = *reinterpret_cast<const f32x4*>(base + (size_t)k * (4 * G3 * 4));
#pragma unroll
    for (int i = 0; i < 4; ++i) m[i] = fmaxf(m[i], fabsf(v[i]));
  }
  __shared__ f32x4 red[256];
  red[threadIdx.x] = m;
  __syncthreads();
  if (threadIdx.x < 64) {
    int t = threadIdx.x;
    f32x4 a = red[t], b2 = red[t + 64], c2 = red[t + 128], d2 = red[t + 192];
    unsigned int* out = cmax + mat * G3 + cg * 256 + t * 4;
#pragma unroll
    for (int i = 0; i < 4; ++i) {
      float mm = fmaxf(fmaxf(a[i], b2[i]), fmaxf(c2[i], d2[i]));
      atomicMax(out + i, __float_as_uint(mm));
    }
  }
}

// Stage B: colmax bits -> fscale = m/127^2 and qinv = 127/m (in place).
__global__ void colscale_fin_k(float* __restrict__ fs,
                               unsigned int* __restrict__ qinv) {
  int i = blockIdx.x * 256 + threadIdx.x;
  float m = __uint_as_float(qinv[i]);
  fs[i] = m * (1.f / 16129.f);
  reinterpret_cast<float*>(qinv)[i] = 127.f / m;
}

// fp32 (2048 x 6144) -> int8 MFMA-tiled (per-column scaled), all 3 matrices.
// lane L of chunk c holds B[k = c*64 + (L>>4)*16 + j][col = ct*16 + (L&15)].
__global__ __launch_bounds__(256) void convert_w_i8(const float* __restrict__ s0,
                                                    const float* __restrict__ s1,
                                                    const float* __restrict__ s2,
                                                    const float* __restrict__ qinv,
                                                    signed char* __restrict__ dst) {
  int mb = blockIdx.x / 3072;
  int tid = (blockIdx.x - mb * 3072) * 256 + threadIdx.x;   // 786432 groups/mat
  const float* src = (mb == 0) ? s0 : (mb == 1) ? s1 : s2;
  const float* qi_ = qinv + mb * G3;
  signed char* d_ = dst + (size_t)mb * 12582912;
  int gg = tid >> 18;
  int rem = tid & 262143;
  int ctc = rem >> 6;          // ct*32 + c
  int L = rem & 63;
  int ct = ctc >> 5, c = ctc & 31;
  int nl = L & 15, kq = L >> 4;
  int ocol = gg * 2048 + ct * 16 + nl;
  int kbase = c * 64 + kq * 16;
  float qi = qi_[ocol];
  union { signed char b[16]; int4 v; } o;
#pragma unroll
  for (int j = 0; j < 16; ++j) {
    int k = kbase + j;
    int q = (int)rintf(src[(size_t)k * G3 + ocol] * qi);
    o.b[j] = (signed char)q;
  }
  *reinterpret_cast<int4*>(d_ + (size_t)tid * 16) = o.v;
}

// fp32 (ksrc x 6144) -> bf16 MFMA-tiled layout (W0K only, K padded to 128).
__global__ void convert_w(const float* __restrict__ src, unsigned short* __restrict__ dst,
                          int ksrc, int kc_shift) {
  int tid = blockIdx.x * 256 + threadIdx.x;
  int nl = tid & 15;
  int kb = (tid >> 4) & 3;
  int kc_mask = (1 << kc_shift) - 1;
  int c  = (tid >> 6) & kc_mask;
  int ct = tid >> (6 + kc_shift);
  int col = ct * 16 + nl;
  int kbase = c * 32 + kb * 8;
  union { unsigned short u[8]; int4 v; } o;
#pragma unroll
  for (int j = 0; j < 8; ++j) {
    int k = kbase + j;
    float v = (k < ksrc) ? src[(size_t)k * G3 + col] : 0.f;
    o.u[j] = f2bf(v);
  }
  *reinterpret_cast<int4*>(dst + (size_t)tid * 8) = o.v;
}

// X[t][b][e] = bf16(emb[tokens[b][t]][e]), e padded to 128 with zeros.
__global__ void embed_k(const int* __restrict__ tokens, const float* __restrict__ emb,
                        unsigned short* __restrict__ X) {
  int idx = blockIdx.x * 256 + threadIdx.x;
  int e = idx & (EP - 1);
  int b = (idx >> 7) & (BB - 1);
  int t = idx >> 14;
  float v = 0.f;
  if (e < EE) {
    int tok = tokens[b * TT + t];
    v = emb[(size_t)tok * EE + e];
  }
  X[idx] = f2bf(v);
}

// Fused step dispatch d (0..80), 256 blocks x 512 threads (8 waves), full-K
// GEMM + inline gate math. Each wave owns 16 output rows (batch), so 2
// waves/SIMD interleave MFMA issue with weight/A-operand loads.
//   blocks [0,128)  (type A): h0(d) for units [blk*16, +16): 3-gate r0 GEMM
//     (K=2048 int8) + x_d@k0 input proj (K=128 bf16) + gates -> H0F/H0Q.
//   blocks [128,256) (type B): h1(d-1): 6 slots = {k1,r1} x 3 gates,
//     K=2048 int8, two A operands (h0(d-1), h1(d-2)) + gates -> H1F/H1Q.
// Quantized state parity double-buffer: h(s) lives in buf[s&1]; readers use
// the previous-parity buffer (no intra-dispatch RAW race); kernel boundaries
// provide cross-XCD visibility.
__global__ __launch_bounds__(512) void step_fused(
    int d,
    const unsigned short* __restrict__ X,
    const unsigned short* __restrict__ W0K,
    const signed char* __restrict__ QW0R, const signed char* __restrict__ QW1K,
    const float* __restrict__ FS0R, const float* __restrict__ FS1K,
    const float* __restrict__ FS1R,
    const float* __restrict__ b0, const float* __restrict__ b1,
    float* __restrict__ H0F, float* __restrict__ H1F,
    signed char* __restrict__ H0Q, signed char* __restrict__ H1Q) {
  int blk = blockIdx.x;
  bool tA = blk < 128;
  if (tA) { if (d >= TT) return; }
  else    { if (d < 1)   return; }
  int ct16 = tA ? blk : blk - 128;
  int lane = threadIdx.x & 63;
  int wave = threadIdx.x >> 6;   // 0..7, owns rows [wave*16, +16)
  int nl = lane & 15, kq = lane >> 4;
  int u = ct16 * 16 + nl;
  int row = wave * 16 + nl;

  __shared__ unsigned char sbuf[2][24576];   // double-buffered weight windows

  const signed char* AqI = H0Q + (size_t)((d + 1) & 1) * PLANE;  // h0(d-1)
  const signed char* AqH = H1Q + (size_t)(d & 1) * PLANE;        // h1(d-2)
  const signed char* apI = AqI + (size_t)row * UU + kq * 16;
  const signed char* apH = AqH + (size_t)row * UU + kq * 16;

  // staging map (512 threads => 3 int4/thread per 24 KB window).
  // LDS byte = ss*16 (ss = i*512 + tid) = wslot*1024 + l16*16.
  //  type A: wslot = kcw*3 + gg         (kcw 0..7, window = 8 K-chunks)
  //  type B: wslot = kcw*6 + mat*3 + gg (kcw 0..3, window = 4 K-chunks)
  // QW1R = QW1K + 12582912 by construction (mat folded into offset).
  const signed char* QWB = tA ? QW0R : QW1K;
  int woff[3];
  int soff0 = threadIdx.x * 16;
  {
    int t = threadIdx.x;
#pragma unroll
    for (int i = 0; i < 3; ++i) {
      int ss = i * 512 + t;
      int wslot = ss >> 6, l16 = ss & 63;
      int off;
      if (tA) {
        int kcw = wslot / 3, gg = wslot - kcw * 3;
        off = gg * 4194304 + (ct16 * 32 + kcw) * 1024 + l16 * 16;
      } else {
        int kcw = wslot / 6, rem = wslot - kcw * 6;
        int mat = rem / 3, gg = rem - mat * 3;
        off = mat * 12582912 + gg * 4194304 + (ct16 * 32 + kcw) * 1024 + l16 * 16;
      }
      woff[i] = off;
    }
  }
  // prologue: window 0
  {
    int4 v[3];
#pragma unroll
    for (int i = 0; i < 3; ++i)
      v[i] = *reinterpret_cast<const int4*>(QWB + (size_t)woff[i]);
#pragma unroll
    for (int i = 0; i < 3; ++i)
      *reinterpret_cast<int4*>(&sbuf[0][soff0 + i * 8192]) = v[i];
  }
  __syncthreads();

  if (tA) {
    // ---- type A: L0, 3 slots, 4 windows of 8 K-chunks ----
    i32x4 acc[3];
#pragma unroll
    for (int gg = 0; gg < 3; ++gg) acc[gg] = {0, 0, 0, 0};

    i32x4 aI = *reinterpret_cast<const i32x4*>(apI);
    i32x4 nI;

#pragma unroll
    for (int w = 0; w < 4; ++w) {
      int4 v[3];
      if (w < 3) {
#pragma unroll
        for (int i = 0; i < 3; ++i)
          v[i] = *reinterpret_cast<const int4*>(QWB + (size_t)woff[i] + (w + 1) * 8192);
      }
#pragma unroll
      for (int kcw = 0; kcw < 8; ++kcw) {
        int kc = w * 8 + kcw;
        if (kc < 31)
          nI = *reinterpret_cast<const i32x4*>(apI + (size_t)(kc + 1) * 64);
#pragma unroll
        for (int gg = 0; gg < 3; ++gg) {
          i32x4 bw = *reinterpret_cast<const i32x4*>(
              &sbuf[w & 1][(kcw * 3 + gg) * 1024 + lane * 16]);
          acc[gg] = __builtin_amdgcn_mfma_i32_16x16x64_i8(aI, bw, acc[gg], 0, 0, 0);
        }
        if (kc < 31) aI = nI;
      }
      if (w < 3) {
#pragma unroll
        for (int i = 0; i < 3; ++i)
          *reinterpret_cast<int4*>(&sbuf[(w + 1) & 1][soff0 + i * 8192]) = v[i];
        __syncthreads();
      }
    }

    // input projection x_d @ k0 (bf16, K=128 padded): iz, ir, ih
    f32x4 ai0 = {0,0,0,0}, ai1 = {0,0,0,0}, ai2 = {0,0,0,0};
    {
      const unsigned short* wp = W0K + (size_t)ct16 * 2048 + (size_t)lane * 8;
      const unsigned short* xp = X + (size_t)d * BB * EP + (size_t)row * EP + kq * 8;
#pragma unroll
      for (int c = 0; c < 4; ++c) {
        bf16x8 a  = *reinterpret_cast<const bf16x8*>(xp + c * 32);
        bf16x8 w0 = *reinterpret_cast<const bf16x8*>(wp + (size_t)0 * 262144 + c * 512);
        bf16x8 w1 = *reinterpret_cast<const bf16x8*>(wp + (size_t)1 * 262144 + c * 512);
        bf16x8 w2 = *reinterpret_cast<const bf16x8*>(wp + (size_t)2 * 262144 + c * 512);
        ai0 = __builtin_amdgcn_mfma_f32_16x16x32_bf16(a, w0, ai0, 0, 0, 0);
        ai1 = __builtin_amdgcn_mfma_f32_16x16x32_bf16(a, w1, ai1, 0, 0, 0);
        ai2 = __builtin_amdgcn_mfma_f32_16x16x32_bf16(a, w2, ai2, 0, 0, 0);
      }
    }

    // gates + state update for h0(d)
    float fsz = FS0R[u], fsr = FS0R[UU + u], fsh = FS0R[2 * UU + u];
    float bz  = b0[u] + b0[G3 + u];
    float br  = b0[UU + u] + b0[G3 + UU + u];
    float bih = b0[2 * UU + u];
    float bhh = b0[G3 + 2 * UU + u];
    signed char* H0Qw = H0Q + (size_t)(d & 1) * PLANE;
    int m0 = wave * 16 + kq * 4;
#pragma unroll
    for (int rr = 0; rr < 4; ++rr) {
      float hz = (float)acc[0][rr] * fsz;
      float hr = (float)acc[1][rr] * fsr;
      float hh = (float)acc[2][rr] * fsh + bhh;
      float z    = sigf(ai0[rr] + hz + bz);
      float rg   = sigf(ai1[rr] + hr + br);
      float cand = tanhfast(ai2[rr] + bih + rg * hh);
      size_t o = (size_t)(m0 + rr) * UU + u;
      float hold = H0F[o];
      float hn = z * hold + (1.f - z) * cand;
      H0F[o] = hn;
      H0Qw[o] = (signed char)(int)rintf(hn * 127.f);
    }
  } else {
    // ---- type B: L1, 6 slots (k1 x 3, r1 x 3), 8 windows of 4 K-chunks ----
    i32x4 acc[6];
#pragma unroll
    for (int s = 0; s < 6; ++s) acc[s] = {0, 0, 0, 0};

    i32x4 aI = *reinterpret_cast<const i32x4*>(apI);
    i32x4 aH = *reinterpret_cast<const i32x4*>(apH);
    i32x4 nI, nH;

#pragma unroll
    for (int w = 0; w < 8; ++w) {
      int4 v[3];
      if (w < 7) {
#pragma unroll
        for (int i = 0; i < 3; ++i)
          v[i] = *reinterpret_cast<const int4*>(QWB + (size_t)woff[i] + (w + 1) * 4096);
      }
#pragma unroll
      for (int kcw = 0; kcw < 4; ++kcw) {
        int kc = w * 4 + kcw;
        if (kc < 31) {
          nI = *reinterpret_cast<const i32x4*>(apI + (size_t)(kc + 1) * 64);
          nH = *reinterpret_cast<const i32x4*>(apH + (size_t)(kc + 1) * 64);
        }
#pragma unroll
        for (int s = 0; s < 6; ++s) {
          i32x4 bw = *reinterpret_cast<const i32x4*>(
              &sbuf[w & 1][(kcw * 6 + s) * 1024 + lane * 16]);
          acc[s] = __builtin_amdgcn_mfma_i32_16x16x64_i8(
              (s < 3) ? aI : aH, bw, acc[s], 0, 0, 0);
        }
        if (kc < 31) { aI = nI; aH = nH; }
      }
      if (w < 7) {
#pragma unroll
        for (int i = 0; i < 3; ++i)
          *reinterpret_cast<int4*>(&sbuf[(w + 1) & 1][soff0 + i * 8192]) = v[i];
        __syncthreads();
      }
    }

    // gates + state update for h1(d-1)
    float fiz = FS1K[u], fir = FS1K[UU + u], fih = FS1K[2 * UU + u];
    float fhz = FS1R[u], fhr = FS1R[UU + u], fhh = FS1R[2 * UU + u];
    float bz  = b1[u] + b1[G3 + u];
    float br  = b1[UU + u] + b1[G3 + UU + u];
    float bih = b1[2 * UU + u];
    float bhh = b1[G3 + 2 * UU + u];
    signed char* H1Qw = H1Q + (size_t)((d + 1) & 1) * PLANE;
    int m0 = wave * 16 + kq * 4;
#pragma unroll
    for (int rr = 0; rr < 4; ++rr) {
      float iz  = (float)acc[0][rr] * fiz;
      float ir  = (float)acc[1][rr] * fir;
      float ihv = (float)acc[2][rr] * fih;
      float hz  = (float)acc[3][rr] * fhz;
      float hr  = (float)acc[4][rr] * fhr;
      float hhv = (float)acc[5][rr] * fhh + bhh;
      float z    = sigf(iz + hz + bz);
      float rg   = sigf(ir + hr + br);
      float cand = tanhfast(ihv + bih + rg * hhv);
      size_t o = (size_t)(m0 + rr) * UU + u;
      float hold = H1F[o];
      float hn = z * hold + (1.f - z) * cand;
      H1F[o] = hn;
      H1Qw[o] = (signed char)(int)rintf(hn * 127.f);
    }
  }
}

// logits = sigmoid(h1 @ wout + bout): 128 blocks x 64 threads, one row each.
__global__ void out_k(const float* __restrict__ h1, const float* __restrict__ wout,
                      const float* __restrict__ bout, float* __restrict__ out) {
  int row = blockIdx.x;
  int lane = threadIdx.x;
  float s = 0.f;
  for (int i = lane; i < UU; i += 64) s += h1[(size_t)row * UU + i] * wout[i];
#pragma unroll
  for (int off = 32; off > 0; off >>= 1) s += __shfl_down(s, off);
  if (lane == 0) out[row] = 1.f / (1.f + __expf(-(s + bout[0])));
}

extern "C" void kernel_launch(void* const* d_in, const int* in_sizes, int n_in,
                              void* d_out, int out_size, void* d_ws, size_t ws_size,
                              hipStream_t stream) {
  const int*   tokens = (const int*)  d_in[0];
  const float* emb    = (const float*)d_in[1];
  const float* k0     = (const float*)d_in[2];
  const float* r0     = (const float*)d_in[3];
  const float* b0     = (const float*)d_in[4];
  const float* k1     = (const float*)d_in[5];
  const float* r1     = (const float*)d_in[6];
  const float* b1     = (const float*)d_in[7];
  const float* wout   = (const float*)d_in[8];
  const float* bout   = (const float*)d_in[9];
  float* out = (float*)d_out;

  char* ws = (char*)d_ws;
  unsigned short* W0K = (unsigned short*)(ws + 0);           //  1.5 MB bf16 tiled
  signed char* QW0R   = (signed char*)(ws + 1572864);        // 12.6 MB int8 tiled
  signed char* QW1K   = (signed char*)(ws + 14155776);       // 12.6 MB
  signed char* QW1R   = (signed char*)(ws + 26738688);       // 12.6 MB (= QW1K + 12582912)
  float* FS0R         = (float*)(ws + 39321600);             // 24 KB dequant scales
  float* FS1K         = (float*)(ws + 39346176);
  float* FS1R         = (float*)(ws + 39370752);
  float* QI0R         = (float*)(ws + 39395328);             // 3 x 24 KB quant inv-scales
  unsigned short* X   = (unsigned short*)(ws + 39469056);    //  2.6 MB bf16
  float* H0F          = (float*)(ws + 42090496);             //  1 MB fp32 state
  float* H1F          = (float*)(ws + 43139072);             //  1 MB
  signed char* H0Q    = (signed char*)(ws + 44187648);       //  2 x 256 KB int8 state (parity)
  signed char* H1Q    = (signed char*)(ws + 44711936);       //  2 x 256 KB
  // total ws use: 45,236,224 bytes
  (void)QW1R;

  // zero state (H0F, H1F, H0Q[2], H1Q[2] contiguous): 3 MiB
  hipMemsetAsync(ws + 42090496, 0, 3145728, stream);
  // zero colmax accumulators (3 x 24 KB)
  hipMemsetAsync(ws + 39395328, 0, 73728, stream);

  // per-column absmax + scale finalize
  colmax_k<<<2304, 256, 0, stream>>>(r0, k1, r1, (unsigned int*)QI0R);
  colscale_fin_k<<<72, 256, 0, stream>>>(FS0R, (unsigned int*)QI0R);

  // int8 tiled conversion, all three matrices in one launch
  convert_w_i8<<<9216, 256, 0, stream>>>(r0, k1, r1, QI0R, QW0R);

  // L0 input-proj weights stay bf16 (tiny, K=128 padded)
  convert_w<<<384, 256, 0, stream>>>(k0, W0K, 100, 2);

  // embedding gather (time-major, padded)
  embed_k<<<5120, 256, 0, stream>>>(tokens, emb, X);

  // 81 fused step dispatches: d computes h0(d) and h1(d-1) in one kernel
  for (int d = 0; d <= TT; ++d) {
    step_fused<<<256, 512, 0, stream>>>(d, X, W0K, QW0R, QW1K,
                                        FS0R, FS1K, FS1R, b0, b1,
                                        H0F, H1F, H0Q, H1Q);
  }

  out_k<<<128, 64, 0, stream>>>(H1F, wout, bout, out);
}